// Round 4
// baseline (283.821 us; speedup 1.0000x reference)
//
#include <hip/hip_runtime.h>
#include <math.h>

#define B_  32
#define N_  256
#define K_  8
#define HW_ 196
#define C_  1000
#define D_  50176            // N_*HW_
#define WK_ 12845056         // N_*N_*HW_ per k

// ws float offsets
#define WS_AH   0            // B*K*HW = 50176
#define WS_DR   50176        // B*K*N  = 65536
#define WS_PART 131072       // 128 chunks * 65536 = 8388608 floats (33.5 MB)

// dim_red tiling: 128 chunks x 8 k = 1024 blocks (4/CU), chunk = 392 d
#define CH_   392
#define NP16_ 24             // 24 phases of 16 floats + 1 tail phase of 8

__device__ __forceinline__ void gload16(const float* g, float* l) {
  __builtin_amdgcn_global_load_lds((const __attribute__((address_space(1))) void*)g,
                                   (__attribute__((address_space(3))) void*)l, 16, 0, 0);
}
#define LGKM0()  asm volatile("s_waitcnt lgkmcnt(0)" ::: "memory")
#define VMC(n)   asm volatile("s_waitcnt vmcnt(" #n ")" ::: "memory")
#define SBAR()   __builtin_amdgcn_s_barrier()
#define FENCE()  asm volatile("" ::: "memory")
#define SCHED0() __builtin_amdgcn_sched_barrier(0)

// ---------------- kernel 1: logits + softmax + loss ----------------
__global__ __launch_bounds__(256) void k_front(const float* __restrict__ x,
                                               const float* __restrict__ cw,
                                               float* __restrict__ ws,
                                               float* __restrict__ out) {
  const int b = blockIdx.x, t = threadIdx.x;
  __shared__ float cwl[K_][N_];
  __shared__ float AH[K_][HW_ + 4];
  __shared__ float red[256];
#pragma unroll
  for (int i = 0; i < 8; ++i) {
    const int idx = i*256 + t;
    cwl[idx >> 8][idx & 255] = cw[idx];
  }
  __syncthreads();
  if (t < HW_) {
    float acc[K_];
#pragma unroll
    for (int k = 0; k < K_; ++k) acc[k] = 0.f;
    const float* xb = x + (size_t)b*D_ + t;
#pragma unroll 4
    for (int n = 0; n < N_; ++n) {
      const float xv = xb[(size_t)n*HW_];
#pragma unroll
      for (int k = 0; k < K_; ++k) acc[k] = fmaf(xv, cwl[k][n], acc[k]);
    }
    float m = acc[0];
#pragma unroll
    for (int k = 1; k < K_; ++k) m = fmaxf(m, acc[k]);
    float s = 0.f;
#pragma unroll
    for (int k = 0; k < K_; ++k) { acc[k] = __expf(acc[k] - m); s += acc[k]; }
    const float inv = 1.f / s;
#pragma unroll
    for (int k = 0; k < K_; ++k) {
      const float a = acc[k] * inv;
      AH[k][t] = a;
      ws[WS_AH + (b*K_ + k)*HW_ + t] = a;
    }
  }
  __syncthreads();
  float l = 0.f;
  if (t < HW_) {                       // G[w,v] contribution
    const int w = t / 14, v2 = t % 14;
    float g = 0.f;
#pragma unroll
    for (int k = 0; k < K_; ++k)
#pragma unroll
      for (int h = 0; h < 14; ++h)
        g = fmaf(AH[k][h*14 + w], AH[k][h*14 + v2], g);
    l = g * g;
  }
  if (t < 112) {                       // loss2
    const int k2 = t / 14, w = t % 14;
    float s = 0.f;
#pragma unroll
    for (int h = 0; h < 14; ++h) s += AH[k2][h*14 + w];
    l -= s * s;
  }
  red[t] = l;
  __syncthreads();
  for (int s2 = 128; s2 > 0; s2 >>= 1) { if (t < s2) red[t] += red[t + s2]; __syncthreads(); }
  if (t == 0) out[256256 + b] = red[0];
}

// ---------------- kernel 2: dim_red — counted-vmcnt double-buffered pipeline ----------------
// 128 threads, per-thread 8b x 8m tile. W rows 16 floats/phase, quad-XOR-swizzled.
__global__ __launch_bounds__(128, 2) void k_dimred(const float* __restrict__ x,
                                                   const float* __restrict__ ah,
                                                   const float* __restrict__ dw,
                                                   float* __restrict__ part) {
  const int chunk = blockIdx.x, k = blockIdx.y;
  const int t = threadIdx.x;
  const int lane = t & 63, wv = t >> 6;
  const int tb = lane >> 4;              // 0..3  -> b = tb + 4i
  const int tm = (lane & 15) + wv*16;    // 0..31 -> m = tm + 32j

  __shared__ float Wl[2][4096];          // [buf][m*16 + slot*4], slot = c ^ ((m>>1)&3)
  __shared__ float Al[2][512];           // [buf][b*16 + c*4]

  const float* Wk = dw + (size_t)k*WK_;
  const int d0 = chunk*CH_;              // multiple of 196 (392 = 2*196)

  // stage-16 W slots: j = i*128+t -> row m=j>>2, slot c=j&3 holds global quad c^((m>>1)&3)
  int woff[8];
#pragma unroll
  for (int i = 0; i < 8; ++i) {
    const int j = i*128 + t;
    const int m = j >> 2, c = j & 3;
    woff[i] = m*D_ + ((c ^ ((m >> 1) & 3)) << 2);
  }
  // tail (8-float) W slots: row m=j>>1, half c=j&1, no swizzle
  int woffT[4];
#pragma unroll
  for (int i = 0; i < 4; ++i) {
    const int j = i*128 + t;
    woffT[i] = (j >> 1)*D_ + ((j & 1) << 2);
  }
  const int ldsW = wv*256;               // DMA base (floats); +i*512 per issue

  // A slot (main phases): e = t -> b = t>>2, c = t&3
  const int ab_ = t >> 2, ac = t & 3;
  const float* xb  = x + (size_t)ab_*D_ + d0 + ac*4;
  const float* ahb = ah + (ab_*K_ + k)*HW_;
  int hw = ac*4;                          // (d0 % 196 == 0); advances +16 mod 196, never straddles
  // A slot (tail): t<64 -> b = t>>1, c = t&1
  const int abT = t >> 1, acT = t & 1;
  const float* xbT  = x + (size_t)abT*D_ + d0 + 384 + acT*4;
  const float* ahbT = ah + (abT*K_ + k)*HW_ + 188 + acT*4;   // (384+c*4) % 196

  float acc[8][8];
#pragma unroll
  for (int i = 0; i < 8; ++i)
#pragma unroll
    for (int j = 0; j < 8; ++j) acc[i][j] = 0.f;

  // ---- prologue: stage phase 0 -> buf0 ----
  {
    const float4 xv = *(const float4*)xb;
    const float4 av = *(const float4*)(ahb + hw);
    SCHED0();
    const float* wb = Wk + d0;
#pragma unroll
    for (int i = 0; i < 8; ++i) gload16(wb + woff[i], &Wl[0][i*512 + ldsW]);
    float4 r;
    r.x = xv.x*av.x; r.y = xv.y*av.y; r.z = xv.z*av.z; r.w = xv.w*av.w;
    *(float4*)&Al[0][4*t] = r;
    hw += 16; if (hw >= HW_) hw -= HW_;
  }

  // ---- main loop: stage(ph+1) -> vmcnt(8) [W(cur) drained, W(nxt) in flight] -> barrier -> compute(ph) ----
  for (int ph = 0; ph < NP16_; ++ph) {
    const int cur = ph & 1, nxt = cur ^ 1;
    if (ph < NP16_ - 1) {
      const float4 xv = *(const float4*)(xb + (ph + 1)*16);
      const float4 av = *(const float4*)(ahb + hw);
      SCHED0();
      const float* wb = Wk + d0 + (ph + 1)*16;
#pragma unroll
      for (int i = 0; i < 8; ++i) gload16(wb + woff[i], &Wl[nxt][i*512 + ldsW]);
      float4 r;
      r.x = xv.x*av.x; r.y = xv.y*av.y; r.z = xv.z*av.z; r.w = xv.w*av.w;
      *(float4*)&Al[nxt][4*t] = r;
      hw += 16; if (hw >= HW_) hw -= HW_;
      VMC(8);                            // drain W(cur)+A; keep W(nxt) 8 loads flying
    } else {
      // stage tail (8 floats) into buf nxt
      float4 xv, av;
      if (t < 64) { xv = *(const float4*)xbT; av = *(const float4*)ahbT; }
      SCHED0();
      const float* wb = Wk + d0 + 384;
#pragma unroll
      for (int i = 0; i < 4; ++i) gload16(wb + woffT[i], &Wl[nxt][i*512 + ldsW]);
      if (t < 64) {
        float4 r;
        r.x = xv.x*av.x; r.y = xv.y*av.y; r.z = xv.z*av.z; r.w = xv.w*av.w;
        *(float4*)&Al[nxt][4*t] = r;
      }
      VMC(4);                            // drain W(cur)+A; keep 4 tail loads flying
    }
    LGKM0();
    SBAR(); FENCE();
    // ---- compute phase ph from [cur] ----
    const int msk = (tm >> 1) & 3;
    const float* Wc = &Wl[cur][tm*16];
    const float* Ac = &Al[cur][tb*16];
#pragma unroll
    for (int q = 0; q < 4; ++q) {
      const int sw = ((q ^ msk) << 2);
      float4 a4[8], w4[8];
#pragma unroll
      for (int i = 0; i < 8; ++i) a4[i] = *(const float4*)(Ac + i*64 + q*4);
#pragma unroll
      for (int j = 0; j < 8; ++j) w4[j] = *(const float4*)(Wc + j*512 + sw);
#pragma unroll
      for (int i = 0; i < 8; ++i)
#pragma unroll
        for (int j = 0; j < 8; ++j) {
          acc[i][j] = fmaf(a4[i].x, w4[j].x, acc[i][j]);
          acc[i][j] = fmaf(a4[i].y, w4[j].y, acc[i][j]);
          acc[i][j] = fmaf(a4[i].z, w4[j].z, acc[i][j]);
          acc[i][j] = fmaf(a4[i].w, w4[j].w, acc[i][j]);
        }
    }
    FENCE(); SBAR(); FENCE();            // all waves done reading [cur]; it may be overwritten
  }

  // ---- tail compute (8 floats, buf0) ----
  VMC(0); LGKM0();
  SBAR(); FENCE();
  {
    const float* Wc = &Wl[0][tm*8];
    const float* Ac = &Al[0][tb*8];
#pragma unroll
    for (int q = 0; q < 2; ++q) {
      float4 a4[8], w4[8];
#pragma unroll
      for (int i = 0; i < 8; ++i) a4[i] = *(const float4*)(Ac + i*32 + q*4);
#pragma unroll
      for (int j = 0; j < 8; ++j) w4[j] = *(const float4*)(Wc + j*256 + q*4);
#pragma unroll
      for (int i = 0; i < 8; ++i)
#pragma unroll
        for (int j = 0; j < 8; ++j) {
          acc[i][j] = fmaf(a4[i].x, w4[j].x, acc[i][j]);
          acc[i][j] = fmaf(a4[i].y, w4[j].y, acc[i][j]);
          acc[i][j] = fmaf(a4[i].z, w4[j].z, acc[i][j]);
          acc[i][j] = fmaf(a4[i].w, w4[j].w, acc[i][j]);
        }
    }
  }

  // ---- store partial tile: part[chunk][(b*K + k)*256 + m] ----
  float* po = part + (size_t)chunk*65536;
#pragma unroll
  for (int i = 0; i < 8; ++i) {
    const int bb = tb + 4*i;
#pragma unroll
    for (int j = 0; j < 8; ++j) {
      po[(bb*K_ + k)*N_ + tm + 32*j] = acc[i][j];
    }
  }
}

// ---------------- kernel 2b: reduce 128 partials -> dr ----------------
__global__ __launch_bounds__(256) void k_reduce(const float* __restrict__ part,
                                                float* __restrict__ dr) {
  const int p4 = blockIdx.x*256 + threadIdx.x;     // float4 index in [0, 16384)
  float4 a = make_float4(0.f, 0.f, 0.f, 0.f);
#pragma unroll 4
  for (int c = 0; c < 128; ++c) {
    const float4 v = *(const float4*)(part + (size_t)c*65536 + p4*4);
    a.x += v.x; a.y += v.y; a.z += v.z; a.w += v.w;
  }
  *(float4*)(dr + p4*4) = a;
}

// ---------------- kernel 3: hyp = dr@Wo^T + b ; conf = tanh(dr@Wg + b) ----------------
__global__ __launch_bounds__(256) void k_out(const float* __restrict__ dr,
                                             const float* __restrict__ db,
                                             const float* __restrict__ Wo,
                                             const float* __restrict__ Wob,
                                             const float* __restrict__ Wg,
                                             const float* __restrict__ Wgb,
                                             float* __restrict__ out) {
  const int ct = blockIdx.x, k = blockIdx.y;
  const int t = threadIdx.x;
  __shared__ float Wl[32][257];
  __shared__ float dl[256][36];
#pragma unroll
  for (int i = 0; i < 32; ++i) {
    const int e = i*256 + t;
    const int row = e >> 8, col = e & 255;
    const int c = ct*32 + row;
    Wl[row][col] = (c < C_) ? Wo[((size_t)(k*C_ + c))*N_ + col] : 0.f;
  }
#pragma unroll
  for (int i = 0; i < 32; ++i) {
    const int e = i*256 + t;
    const int n = e & 255, b = e >> 8;
    dl[n][b] = dr[(b*K_ + k)*N_ + n] + db[k*N_ + n];
  }
  __syncthreads();
  const int tc = t & 31, tg = t >> 5;
  const int c = ct*32 + tc;
  float a0=0.f, a1=0.f, a2=0.f, a3=0.f;
#pragma unroll 8
  for (int n = 0; n < N_; ++n) {
    const float wvv = Wl[tc][n];
    const float4 dv = *(const float4*)&dl[n][tg*4];
    a0 = fmaf(wvv, dv.x, a0);
    a1 = fmaf(wvv, dv.y, a1);
    a2 = fmaf(wvv, dv.z, a2);
    a3 = fmaf(wvv, dv.w, a3);
  }
  if (c < C_) {
    const float bias = Wob[k*C_ + c];
    out[((size_t)(tg*4 + 0)*K_ + k)*C_ + c] = a0 + bias;
    out[((size_t)(tg*4 + 1)*K_ + k)*C_ + c] = a1 + bias;
    out[((size_t)(tg*4 + 2)*K_ + k)*C_ + c] = a2 + bias;
    out[((size_t)(tg*4 + 3)*K_ + k)*C_ + c] = a3 + bias;
  }
  if (ct == 0 && t < B_) {
    float s = Wgb[k];
    for (int n = 0; n < N_; ++n) s = fmaf(dl[n][t], Wg[k*N_ + n], s);
    out[256000 + t*K_ + k] = tanhf(s);
  }
}

extern "C" void kernel_launch(void* const* d_in, const int* in_sizes, int n_in,
                              void* d_out, int out_size, void* d_ws, size_t ws_size,
                              hipStream_t stream) {
  const float* x   = (const float*)d_in[0];
  const float* cw  = (const float*)d_in[1];
  const float* dw  = (const float*)d_in[2];
  const float* db  = (const float*)d_in[3];
  const float* Wo  = (const float*)d_in[4];
  const float* Wob = (const float*)d_in[5];
  const float* Wg  = (const float*)d_in[6];
  const float* Wgb = (const float*)d_in[7];
  float* out = (float*)d_out;
  float* ws  = (float*)d_ws;

  k_front<<<32, 256, 0, stream>>>(x, cw, ws, out);
  k_dimred<<<dim3(128, 8), 128, 0, stream>>>(x, ws + WS_AH, dw, ws + WS_PART);
  k_reduce<<<64, 256, 0, stream>>>(ws + WS_PART, ws + WS_DR);
  k_out<<<dim3(32, 8), 256, 0, stream>>>(ws + WS_DR, db, Wo, Wob, Wg, Wgb, out);
}

// Round 5
// 237.006 us; speedup vs baseline: 1.1975x; 1.1975x over previous
//
#include <hip/hip_runtime.h>
#include <math.h>

#define B_  32
#define N_  256
#define K_  8
#define HW_ 196
#define C_  1000
#define D_  50176            // N_*HW_
#define WK_ 12845056         // N_*N_*HW_ per k

// ws float offsets
#define WS_AH   0            // B*K*HW = 50176
#define WS_DR   50176        // B*K*N  = 65536
#define WS_PART 115712       // 1568 * 2048 floats = 12.85 MB

// dim_red tiling: 49 chunks x 4 m-groups x 8 k = 1568 blocks
#define NCH 49
#define CHD 1024             // d per chunk (49*1024 = 50176)
#define PHD 128              // d per phase
#define NPH 8

typedef __attribute__((ext_vector_type(8))) short short8;
typedef __attribute__((ext_vector_type(4))) float f32x4;

// fp32 -> bf16 RNE, packed pair into u32
__device__ __forceinline__ unsigned pk2(float a, float b) {
  unsigned ua = __builtin_bit_cast(unsigned, a);
  unsigned ub = __builtin_bit_cast(unsigned, b);
  ua = (ua + 0x7fffu + ((ua >> 16) & 1u)) >> 16;
  ub = (ub + 0x7fffu + ((ub >> 16) & 1u)) & 0xffff0000u;
  return ub | ua;
}

// ---------------- kernel 1: logits + softmax + loss ----------------
__global__ __launch_bounds__(256) void k_front(const float* __restrict__ x,
                                               const float* __restrict__ cw,
                                               float* __restrict__ ws,
                                               float* __restrict__ out) {
  const int b = blockIdx.x, t = threadIdx.x;
  __shared__ float cwl[K_][N_];
  __shared__ float AH[K_][HW_ + 4];
  __shared__ float red[256];
#pragma unroll
  for (int i = 0; i < 8; ++i) {
    const int idx = i*256 + t;
    cwl[idx >> 8][idx & 255] = cw[idx];
  }
  __syncthreads();
  if (t < HW_) {
    float acc[K_];
#pragma unroll
    for (int k = 0; k < K_; ++k) acc[k] = 0.f;
    const float* xb = x + (size_t)b*D_ + t;
#pragma unroll 4
    for (int n = 0; n < N_; ++n) {
      const float xv = xb[(size_t)n*HW_];
#pragma unroll
      for (int k = 0; k < K_; ++k) acc[k] = fmaf(xv, cwl[k][n], acc[k]);
    }
    float m = acc[0];
#pragma unroll
    for (int k = 1; k < K_; ++k) m = fmaxf(m, acc[k]);
    float s = 0.f;
#pragma unroll
    for (int k = 0; k < K_; ++k) { acc[k] = __expf(acc[k] - m); s += acc[k]; }
    const float inv = 1.f / s;
#pragma unroll
    for (int k = 0; k < K_; ++k) {
      const float a = acc[k] * inv;
      AH[k][t] = a;
      ws[WS_AH + (b*K_ + k)*HW_ + t] = a;
    }
  }
  __syncthreads();
  float l = 0.f;
  if (t < HW_) {                       // G[w,v] contribution
    const int w = t / 14, v2 = t % 14;
    float g = 0.f;
#pragma unroll
    for (int k = 0; k < K_; ++k)
#pragma unroll
      for (int h = 0; h < 14; ++h)
        g = fmaf(AH[k][h*14 + w], AH[k][h*14 + v2], g);
    l = g * g;
  }
  if (t < 112) {                       // loss2
    const int k2 = t / 14, w = t % 14;
    float s = 0.f;
#pragma unroll
    for (int h = 0; h < 14; ++h) s += AH[k2][h*14 + w];
    l -= s * s;
  }
  red[t] = l;
  __syncthreads();
  for (int s2 = 128; s2 > 0; s2 >>= 1) { if (t < s2) red[t] += red[t + s2]; __syncthreads(); }
  if (t == 0) out[256256 + b] = red[0];
}

// ---------------- kernel 2: dim_red via MFMA bf16 ----------------
// Block: (chunk, mg, k). Output tile 32b x 64m. 4 waves; wave wv owns m-cols wv*16..+15.
// Per phase: W 64x128 fp32 global -> regs -> bf16 LDS (swizzled); A 32x128 from x*ah -> bf16 LDS.
__global__ __launch_bounds__(256) void k_dimred(const float* __restrict__ x,
                                                const float* __restrict__ ah,
                                                const float* __restrict__ dw,
                                                float* __restrict__ part) {
  const int bid = blockIdx.x;
  const int chunk = bid % NCH;
  const int mg    = (bid / NCH) & 3;
  const int k     = bid / (NCH*4);
  const int t = threadIdx.x;
  const int lane = t & 63, wv = t >> 6;

  __shared__ char Wl[2][64*256];       // 64 rows x 128 bf16 (256B), XOR-swizzled 16B slots
  __shared__ char Al[2][32*256];       // 32 rows x 128 bf16

  const int d0 = chunk * CHD;

  // ---- W staging geometry: thread t -> row wm = t>>2, d-seg (t&3)*32
  const int wm = t >> 2, wc = t & 3;
  const float* wg = dw + (size_t)k*WK_ + (size_t)(mg*64 + wm)*D_ + d0 + wc*32;
  int wbyte[4];
#pragma unroll
  for (int q = 0; q < 4; ++q)
    wbyte[q] = wm*256 + ((wc*64 + q*16) ^ ((wm & 7) << 4));

  // ---- A staging geometry: thread t -> row ab = t>>3, d-seg (t&7)*16
  const int ab = t >> 3, ac = t & 7;
  const float* xg = x + (size_t)ab*D_ + d0 + ac*16;
  const float* ag = ah + (ab*K_ + k)*HW_;
  int abyte[2];
#pragma unroll
  for (int q = 0; q < 2; ++q)
    abyte[q] = ab*256 + ((ac*32 + q*16) ^ ((ab & 7) << 4));
  int hw = (d0 + ac*16) % HW_;         // advances +128 mod 196 per phase

  f32x4 wr[8], xr[4];
  f32x4 acc0 = {0.f,0.f,0.f,0.f}, acc1 = {0.f,0.f,0.f,0.f};

  // fragment read geometry
  const int rsw  = (lane & 7) << 4;    // row swizzle (same for A rows l&15, 16+(l&15), W row wv*16+(l&15))
  const int kgb  = (lane >> 4) * 16;   // k-group byte offset within row
  const char* wrow = &Wl[0][0] + (wv*16 + (lane & 15))*256;
  const char* arow0 = &Al[0][0] + (lane & 15)*256;
  const char* arow1 = &Al[0][0] + (16 + (lane & 15))*256;
  const int bufW = 64*256, bufA = 32*256;

  auto load_phase = [&](int ph) {
    const float* wp = wg + ph*PHD;
#pragma unroll
    for (int i = 0; i < 8; ++i) wr[i] = *(const f32x4*)(wp + i*4);
    const float* xp = xg + ph*PHD;
#pragma unroll
    for (int i = 0; i < 4; ++i) xr[i] = *(const f32x4*)(xp + i*4);
  };

  auto store_phase = [&](int buf) {
    // W: 32 floats -> 4x 16B
#pragma unroll
    for (int q = 0; q < 4; ++q) {
      uint4 v;
      v.x = pk2(wr[2*q].x,   wr[2*q].y);
      v.y = pk2(wr[2*q].z,   wr[2*q].w);
      v.z = pk2(wr[2*q+1].x, wr[2*q+1].y);
      v.w = pk2(wr[2*q+1].z, wr[2*q+1].w);
      *(uint4*)(&Wl[buf][0] + wbyte[q]) = v;
    }
    // A: 16 elems = x * ah[d%196]
    float av[16];
#pragma unroll
    for (int j = 0; j < 16; ++j) {
      int hwj = hw + j; if (hwj >= HW_) hwj -= HW_;
      av[j] = xr[j >> 2][j & 3] * ag[hwj];
    }
#pragma unroll
    for (int q = 0; q < 2; ++q) {
      uint4 v;
      v.x = pk2(av[q*8+0], av[q*8+1]);
      v.y = pk2(av[q*8+2], av[q*8+3]);
      v.z = pk2(av[q*8+4], av[q*8+5]);
      v.w = pk2(av[q*8+6], av[q*8+7]);
      *(uint4*)(&Al[buf][0] + abyte[q]) = v;
    }
    hw += PHD; if (hw >= HW_) hw -= HW_;
  };

  // ---- prologue ----
  load_phase(0);
  store_phase(0);
  __syncthreads();

  // ---- main loop: prefetch(ph+1) to regs || MFMA(ph) || cvt+write(ph+1) ----
  for (int ph = 0; ph < NPH; ++ph) {
    const int cur = ph & 1;
    if (ph < NPH - 1) load_phase(ph + 1);
#pragma unroll
    for (int ks = 0; ks < 4; ++ks) {
      const int off = (ks*64 + kgb) ^ rsw;
      short8 wf  = *(const short8*)(wrow  + cur*bufW + off);
      short8 af0 = *(const short8*)(arow0 + cur*bufA + off);
      short8 af1 = *(const short8*)(arow1 + cur*bufA + off);
      acc0 = __builtin_amdgcn_mfma_f32_16x16x32_bf16(af0, wf, acc0, 0, 0, 0);
      acc1 = __builtin_amdgcn_mfma_f32_16x16x32_bf16(af1, wf, acc1, 0, 0, 0);
    }
    if (ph < NPH - 1) store_phase((ph + 1) & 1);
    __syncthreads();
  }

  // ---- store partial tile: part[bid][b*64 + ml] ----
  float* po = part + (size_t)bid*2048;
  const int ml = wv*16 + (lane & 15);
  const int br = (lane >> 4)*4;
#pragma unroll
  for (int r = 0; r < 4; ++r) {
    po[(br + r)*64 + ml]        = acc0[r];
    po[(16 + br + r)*64 + ml]   = acc1[r];
  }
}

// ---------------- kernel 2b: reduce 49 chunks -> dr ----------------
__global__ __launch_bounds__(256) void k_reduce(const float* __restrict__ part,
                                                float* __restrict__ dr) {
  const int tg = blockIdx.x*256 + threadIdx.x;   // (b*8 + k)*256 + m
  const int m = tg & 255, k = (tg >> 8) & 7, b = tg >> 11;
  const int mgr = m >> 6, ml = m & 63;
  const float* p = part + ((size_t)(k*(NCH*4) + mgr*NCH))*2048 + b*64 + ml;
  float s = 0.f;
#pragma unroll 7
  for (int c = 0; c < NCH; ++c) s += p[(size_t)c*2048];
  dr[tg] = s;
}

// ---------------- kernel 3: hyp = dr@Wo^T + b ; conf = tanh(dr@Wg + b) ----------------
__global__ __launch_bounds__(256) void k_out(const float* __restrict__ dr,
                                             const float* __restrict__ db,
                                             const float* __restrict__ Wo,
                                             const float* __restrict__ Wob,
                                             const float* __restrict__ Wg,
                                             const float* __restrict__ Wgb,
                                             float* __restrict__ out) {
  const int ct = blockIdx.x, k = blockIdx.y;
  const int t = threadIdx.x;
  __shared__ float Wl[32][257];
  __shared__ float dl[256][36];
#pragma unroll
  for (int i = 0; i < 32; ++i) {
    const int e = i*256 + t;
    const int row = e >> 8, col = e & 255;
    const int c = ct*32 + row;
    Wl[row][col] = (c < C_) ? Wo[((size_t)(k*C_ + c))*N_ + col] : 0.f;
  }
#pragma unroll
  for (int i = 0; i < 32; ++i) {
    const int e = i*256 + t;
    const int n = e & 255, b = e >> 8;
    dl[n][b] = dr[(b*K_ + k)*N_ + n] + db[k*N_ + n];
  }
  __syncthreads();
  const int tc = t & 31, tg = t >> 5;
  const int c = ct*32 + tc;
  float a0=0.f, a1=0.f, a2=0.f, a3=0.f;
#pragma unroll 8
  for (int n = 0; n < N_; ++n) {
    const float wvv = Wl[tc][n];
    const float4 dv = *(const float4*)&dl[n][tg*4];
    a0 = fmaf(wvv, dv.x, a0);
    a1 = fmaf(wvv, dv.y, a1);
    a2 = fmaf(wvv, dv.z, a2);
    a3 = fmaf(wvv, dv.w, a3);
  }
  if (c < C_) {
    const float bias = Wob[k*C_ + c];
    out[((size_t)(tg*4 + 0)*K_ + k)*C_ + c] = a0 + bias;
    out[((size_t)(tg*4 + 1)*K_ + k)*C_ + c] = a1 + bias;
    out[((size_t)(tg*4 + 2)*K_ + k)*C_ + c] = a2 + bias;
    out[((size_t)(tg*4 + 3)*K_ + k)*C_ + c] = a3 + bias;
  }
  if (ct == 0 && t < B_) {
    float s = Wgb[k];
    for (int n = 0; n < N_; ++n) s = fmaf(dl[n][t], Wg[k*N_ + n], s);
    out[256000 + t*K_ + k] = tanhf(s);
  }
}

extern "C" void kernel_launch(void* const* d_in, const int* in_sizes, int n_in,
                              void* d_out, int out_size, void* d_ws, size_t ws_size,
                              hipStream_t stream) {
  const float* x   = (const float*)d_in[0];
  const float* cw  = (const float*)d_in[1];
  const float* dw  = (const float*)d_in[2];
  const float* db  = (const float*)d_in[3];
  const float* Wo  = (const float*)d_in[4];
  const float* Wob = (const float*)d_in[5];
  const float* Wg  = (const float*)d_in[6];
  const float* Wgb = (const float*)d_in[7];
  float* out = (float*)d_out;
  float* ws  = (float*)d_ws;

  k_front<<<32, 256, 0, stream>>>(x, cw, ws, out);
  k_dimred<<<NCH*4*K_, 256, 0, stream>>>(x, ws + WS_AH, dw, ws + WS_PART);
  k_reduce<<<256, 256, 0, stream>>>(ws + WS_PART, ws + WS_DR);
  k_out<<<dim3(32, 8), 256, 0, stream>>>(ws + WS_DR, db, Wo, Wob, Wg, Wgb, out);
}

// Round 7
// 190.621 us; speedup vs baseline: 1.4889x; 1.2433x over previous
//
#include <hip/hip_runtime.h>
#include <math.h>

#define B_  32
#define N_  256
#define K_  8
#define HW_ 196
#define C_  1000
#define D_  50176            // N_*HW_
#define WK_ 12845056         // N_*N_*HW_ per k

// ws float offsets
#define WS_AH   0            // B*K*HW = 50176 floats
#define WS_DR   50176        // B*K*N  = 65536 floats
#define WS_PART 115712       // 1568 * 2048 floats
#define WS_ABF  3326976      // B*K*D bf16 = 6422528 float-slots (25.7 MB)

// dim_red tiling: 49 chunks x 4 m-groups x 8 k = 1568 blocks
#define NCH 49
#define CHD 1024             // d per chunk
#define PHD 128              // d per phase
#define NPH 8

typedef __attribute__((ext_vector_type(8))) short short8;
typedef __attribute__((ext_vector_type(4))) float f32x4;
typedef unsigned short bf16u;   // bf16 as raw bits (we only ever bit-pack)

// fp32 -> bf16 RNE, packed pair into u32
__device__ __forceinline__ unsigned pk2(float a, float b) {
  unsigned ua = __builtin_bit_cast(unsigned, a);
  unsigned ub = __builtin_bit_cast(unsigned, b);
  ua = (ua + 0x7fffu + ((ua >> 16) & 1u)) >> 16;
  ub = (ub + 0x7fffu + ((ub >> 16) & 1u)) & 0xffff0000u;
  return ub | ua;
}

// ---------------- kernel 1: logits + softmax + loss ----------------
__global__ __launch_bounds__(256) void k_front(const float* __restrict__ x,
                                               const float* __restrict__ cw,
                                               float* __restrict__ ws,
                                               float* __restrict__ out) {
  const int b = blockIdx.x, t = threadIdx.x;
  __shared__ float cwl[K_][N_];
  __shared__ float AH[K_][HW_ + 4];
  __shared__ float red[256];
#pragma unroll
  for (int i = 0; i < 8; ++i) {
    const int idx = i*256 + t;
    cwl[idx >> 8][idx & 255] = cw[idx];
  }
  __syncthreads();
  if (t < HW_) {
    float acc[K_];
#pragma unroll
    for (int k = 0; k < K_; ++k) acc[k] = 0.f;
    const float* xb = x + (size_t)b*D_ + t;
#pragma unroll 4
    for (int n = 0; n < N_; ++n) {
      const float xv = xb[(size_t)n*HW_];
#pragma unroll
      for (int k = 0; k < K_; ++k) acc[k] = fmaf(xv, cwl[k][n], acc[k]);
    }
    float m = acc[0];
#pragma unroll
    for (int k = 1; k < K_; ++k) m = fmaxf(m, acc[k]);
    float s = 0.f;
#pragma unroll
    for (int k = 0; k < K_; ++k) { acc[k] = __expf(acc[k] - m); s += acc[k]; }
    const float inv = 1.f / s;
#pragma unroll
    for (int k = 0; k < K_; ++k) {
      const float a = acc[k] * inv;
      AH[k][t] = a;
      ws[WS_AH + (b*K_ + k)*HW_ + t] = a;
    }
  }
  __syncthreads();
  float l = 0.f;
  if (t < HW_) {                       // G[w,v] contribution
    const int w = t / 14, v2 = t % 14;
    float g = 0.f;
#pragma unroll
    for (int k = 0; k < K_; ++k)
#pragma unroll
      for (int h = 0; h < 14; ++h)
        g = fmaf(AH[k][h*14 + w], AH[k][h*14 + v2], g);
    l = g * g;
  }
  if (t < 112) {                       // loss2
    const int k2 = t / 14, w = t % 14;
    float s = 0.f;
#pragma unroll
    for (int h = 0; h < 14; ++h) s += AH[k2][h*14 + w];
    l -= s * s;
  }
  red[t] = l;
  __syncthreads();
  for (int s2 = 128; s2 > 0; s2 >>= 1) { if (t < s2) red[t] += red[t + s2]; __syncthreads(); }
  if (t == 0) out[256256 + b] = red[0];
}

// ---------------- kernel 1b: materialize A = x*ah as bf16  [B*K, D] ----------------
__global__ __launch_bounds__(256) void k_amat(const float* __restrict__ x,
                                              const float* __restrict__ ah,
                                              bf16u* __restrict__ abf) {
  const int chunk = blockIdx.x, b = blockIdx.y;
  const int t = threadIdx.x;
  __shared__ float ahl[K_][HW_ + 4];
  if (t < HW_) {
#pragma unroll
    for (int k = 0; k < K_; ++k) ahl[k][t] = ah[(b*K_ + k)*HW_ + t];
  }
  const int d = chunk*CHD + t*4;
  const float4 xv = *(const float4*)(x + (size_t)b*D_ + d);
  int h0 = d % HW_;
  int h1 = h0 + 1; if (h1 >= HW_) h1 -= HW_;
  int h2 = h0 + 2; if (h2 >= HW_) h2 -= HW_;
  int h3 = h0 + 3; if (h3 >= HW_) h3 -= HW_;
  __syncthreads();
#pragma unroll
  for (int k = 0; k < K_; ++k) {
    uint2 v;
    v.x = pk2(xv.x*ahl[k][h0], xv.y*ahl[k][h1]);
    v.y = pk2(xv.z*ahl[k][h2], xv.w*ahl[k][h3]);
    *(uint2*)(abf + (size_t)(b*K_ + k)*D_ + d) = v;
  }
}

// ---------------- kernel 2: dim_red via MFMA bf16, fully-coalesced staging ----------------
// Block (chunk, mg, k): output 32b x 64m. Per phase: W 64x128 fp32 -> regs -> bf16 LDS;
// A 32x128 bf16 direct. Every VMEM instr reads contiguous 1KB (full cache lines).
__global__ __launch_bounds__(256, 3) void k_dimred(const float* __restrict__ dw,
                                                   const bf16u* __restrict__ abf,
                                                   float* __restrict__ part) {
  const int bid = blockIdx.x;
  const int chunk = bid % NCH;
  const int mg    = (bid / NCH) & 3;
  const int k     = bid / (NCH*4);
  const int t = threadIdx.x;
  const int lane = t & 63, wv = t >> 6;

  __shared__ __align__(16) char Wl[2][64*256];   // 64 rows x 128 bf16, 16B-slot XOR swizzle
  __shared__ __align__(16) char Al[2][32*256];   // 32 rows x 128 bf16

  const int d0 = chunk * CHD;

  // ---- W staging: instr i reads rows (wv*16 + 2i + (lane>>5)), bytes (lane&31)*16 of the 512B row-span
  const int wrow0 = wv*16 + (lane >> 5);         // +2i
  const int wcolf = (lane & 31)*4;               // float offset within 128-float phase row
  const float* wg = dw + (size_t)k*WK_ + (size_t)(mg*64)*D_ + d0 + wcolf;
  int woff[8], wbyt[8];
#pragma unroll
  for (int i = 0; i < 8; ++i) {
    const int r = wrow0 + 2*i;
    woff[i] = r*D_;
    wbyt[i] = r*256 + (((lane & 31)*8) ^ ((r & 7) << 4));
  }

  // ---- A staging: instr j reads rows (wv*8 + j*4 + (lane>>4)), bytes (lane&15)*16 of 256B row
  int aoff[2], abyt[2];
#pragma unroll
  for (int j = 0; j < 2; ++j) {
    const int r = wv*8 + j*4 + (lane >> 4);
    aoff[j] = (r*K_ + k)*D_ + d0 + (lane & 15)*8;   // bf16 elements
    abyt[j] = r*256 + (((lane & 15)*16) ^ ((r & 7) << 4));
  }

  f32x4 wr[8];
  uint4  ar[2];
  f32x4 acc0 = {0.f,0.f,0.f,0.f}, acc1 = {0.f,0.f,0.f,0.f};

  // fragment read geometry (identical to validated R5 image)
  const int rsw = (lane & 7) << 4;
  const int kgb = (lane >> 4) * 16;
  const char* wrow = &Wl[0][0] + (wv*16 + (lane & 15))*256;
  const char* arow0 = &Al[0][0] + (lane & 15)*256;
  const char* arow1 = &Al[0][0] + (16 + (lane & 15))*256;
  const int bufW = 64*256, bufA = 32*256;

  auto load_phase = [&](int ph) {
    const float* wp = wg + ph*PHD;
#pragma unroll
    for (int i = 0; i < 8; ++i) wr[i] = *(const f32x4*)(wp + woff[i]);
    const int ao = ph*PHD;
#pragma unroll
    for (int j = 0; j < 2; ++j) ar[j] = *(const uint4*)(abf + aoff[j] + ao);
  };

  auto store_phase = [&](int buf) {
#pragma unroll
    for (int i = 0; i < 8; ++i) {
      uint2 v;
      v.x = pk2(wr[i].x, wr[i].y);
      v.y = pk2(wr[i].z, wr[i].w);
      *(uint2*)(&Wl[buf][0] + wbyt[i]) = v;
    }
#pragma unroll
    for (int j = 0; j < 2; ++j)
      *(uint4*)(&Al[buf][0] + abyt[j]) = ar[j];
  };

  // ---- prologue ----
  load_phase(0);
  store_phase(0);
  __syncthreads();

  // ---- main loop: prefetch(ph+1) regs || MFMA(ph) || store(ph+1) ----
  for (int ph = 0; ph < NPH; ++ph) {
    const int cur = ph & 1;
    if (ph < NPH - 1) load_phase(ph + 1);
#pragma unroll
    for (int ks = 0; ks < 4; ++ks) {
      const int off = (ks*64 + kgb) ^ rsw;
      short8 wf  = *(const short8*)(wrow  + cur*bufW + off);
      short8 af0 = *(const short8*)(arow0 + cur*bufA + off);
      short8 af1 = *(const short8*)(arow1 + cur*bufA + off);
      acc0 = __builtin_amdgcn_mfma_f32_16x16x32_bf16(af0, wf, acc0, 0, 0, 0);
      acc1 = __builtin_amdgcn_mfma_f32_16x16x32_bf16(af1, wf, acc1, 0, 0, 0);
    }
    if (ph < NPH - 1) store_phase((ph + 1) & 1);
    __syncthreads();
  }

  // ---- store partial tile: part[bid][b*64 + ml] ----
  float* po = part + (size_t)bid*2048;
  const int ml = wv*16 + (lane & 15);
  const int br = (lane >> 4)*4;
#pragma unroll
  for (int r = 0; r < 4; ++r) {
    po[(br + r)*64 + ml]      = acc0[r];
    po[(16 + br + r)*64 + ml] = acc1[r];
  }
}

// ---------------- kernel 2b: reduce 49 chunks -> dr ----------------
__global__ __launch_bounds__(256) void k_reduce(const float* __restrict__ part,
                                                float* __restrict__ dr) {
  const int tg = blockIdx.x*256 + threadIdx.x;   // (b*8 + k)*256 + m
  const int m = tg & 255, k = (tg >> 8) & 7, b = tg >> 11;
  const int mgr = m >> 6, ml = m & 63;
  const float* p = part + ((size_t)(k*(NCH*4) + mgr*NCH))*2048 + b*64 + ml;
  float s = 0.f;
#pragma unroll 7
  for (int c = 0; c < NCH; ++c) s += p[(size_t)c*2048];
  dr[tg] = s;
}

// ---------------- kernel 3: hyp = dr@Wo^T + b ; conf = tanh(dr@Wg + b) ----------------
__global__ __launch_bounds__(256) void k_out(const float* __restrict__ dr,
                                             const float* __restrict__ db,
                                             const float* __restrict__ Wo,
                                             const float* __restrict__ Wob,
                                             const float* __restrict__ Wg,
                                             const float* __restrict__ Wgb,
                                             float* __restrict__ out) {
  const int ct = blockIdx.x, k = blockIdx.y;
  const int t = threadIdx.x;
  __shared__ float Wl[32][257];
  __shared__ float dl[256][36];
#pragma unroll
  for (int i = 0; i < 32; ++i) {
    const int e = i*256 + t;
    const int row = e >> 8, col = e & 255;
    const int c = ct*32 + row;
    Wl[row][col] = (c < C_) ? Wo[((size_t)(k*C_ + c))*N_ + col] : 0.f;
  }
#pragma unroll
  for (int i = 0; i < 32; ++i) {
    const int e = i*256 + t;
    const int n = e & 255, b = e >> 8;
    dl[n][b] = dr[(b*K_ + k)*N_ + n] + db[k*N_ + n];
  }
  __syncthreads();
  const int tc = t & 31, tg = t >> 5;
  const int c = ct*32 + tc;
  float a0=0.f, a1=0.f, a2=0.f, a3=0.f;
#pragma unroll 8
  for (int n = 0; n < N_; ++n) {
    const float wvv = Wl[tc][n];
    const float4 dv = *(const float4*)&dl[n][tg*4];
    a0 = fmaf(wvv, dv.x, a0);
    a1 = fmaf(wvv, dv.y, a1);
    a2 = fmaf(wvv, dv.z, a2);
    a3 = fmaf(wvv, dv.w, a3);
  }
  if (c < C_) {
    const float bias = Wob[k*C_ + c];
    out[((size_t)(tg*4 + 0)*K_ + k)*C_ + c] = a0 + bias;
    out[((size_t)(tg*4 + 1)*K_ + k)*C_ + c] = a1 + bias;
    out[((size_t)(tg*4 + 2)*K_ + k)*C_ + c] = a2 + bias;
    out[((size_t)(tg*4 + 3)*K_ + k)*C_ + c] = a3 + bias;
  }
  if (ct == 0 && t < B_) {
    float s = Wgb[k];
    for (int n = 0; n < N_; ++n) s = fmaf(dl[n][t], Wg[k*N_ + n], s);
    out[256000 + t*K_ + k] = tanhf(s);
  }
}

extern "C" void kernel_launch(void* const* d_in, const int* in_sizes, int n_in,
                              void* d_out, int out_size, void* d_ws, size_t ws_size,
                              hipStream_t stream) {
  const float* x   = (const float*)d_in[0];
  const float* cw  = (const float*)d_in[1];
  const float* dw  = (const float*)d_in[2];
  const float* db  = (const float*)d_in[3];
  const float* Wo  = (const float*)d_in[4];
  const float* Wob = (const float*)d_in[5];
  const float* Wg  = (const float*)d_in[6];
  const float* Wgb = (const float*)d_in[7];
  float* out = (float*)d_out;
  float* ws  = (float*)d_ws;
  bf16u* abf = (bf16u*)(ws + WS_ABF);

  k_front<<<32, 256, 0, stream>>>(x, cw, ws, out);
  k_amat<<<dim3(NCH, B_), 256, 0, stream>>>(x, ws + WS_AH, abf);
  k_dimred<<<NCH*4*K_, 256, 0, stream>>>(dw, abf, ws + WS_PART);
  k_reduce<<<256, 256, 0, stream>>>(ws + WS_PART, ws + WS_DR);
  k_out<<<dim3(32, 8), 256, 0, stream>>>(ws + WS_DR, db, Wo, Wob, Wg, Wgb, out);
}